// Round 1
// baseline (10030.603 us; speedup 1.0000x reference)
//
#include <hip/hip_runtime.h>
#include <math.h>

#define N_NODES 50000
#define N_EDGES 800000
#define D 128
#define AVG_D_LOG 2.833213344056216f  /* log(17.0) */
#define EPS 1e-5f

// ---------------- init: zero accumulators, +inf for min ----------------
__global__ void k_init(float* deg, float* s1, float* s2, float* mx, float* mn) {
    size_t stride = (size_t)gridDim.x * blockDim.x;
    size_t i0 = (size_t)blockIdx.x * blockDim.x + threadIdx.x;
    const size_t ND = (size_t)N_NODES * D;
    for (size_t t = i0; t < ND; t += stride) {
        s1[t] = 0.f; s2[t] = 0.f; mx[t] = 0.f;
        ((int*)mn)[t] = 0x7f800000;  // +inf
    }
    for (size_t t = i0; t < N_NODES; t += stride) deg[t] = 0.f;
}

// ---------------- pretrans edge MLP + fused scatter ----------------
// tile: 64 edges x 128 out, K=384 in 6 chunks of 64. 256 threads,
// each thread owns 4 edges x 8 channels.
__global__ __launch_bounds__(256) void k_pretrans(
    const float* __restrict__ nf, const float* __restrict__ ef,
    const float* __restrict__ wp, const float* __restrict__ bp,
    const int* __restrict__ src, const int* __restrict__ dst,
    float* s1, float* s2, float* mx, float* mn, float* deg)
{
    __shared__ float zt[64][68];   // [k_local][edge], pad 68 (16B-aligned rows)
    __shared__ float wt[64][128];  // [k_local][channel]
    __shared__ int sidx[64], didx[64];

    int t = threadIdx.x;
    int e0 = blockIdx.x * 64;
    if (t < 64) { sidx[t] = src[e0 + t]; didx[t] = dst[e0 + t]; }
    __syncthreads();
    if (t < 64) atomicAdd(&deg[didx[t]], 1.0f);

    int tc = t & 15;   // channel group: channels tc*8..tc*8+7
    int te = t >> 4;   // edge group:    edges te*4..te*4+3
    float acc[4][8] = {};

    for (int chunk = 0; chunk < 6; ++chunk) {
        int k0 = chunk * 64;
        // stage z chunk: 64 edges x 64 k
        {
            int kl = t & 63;
            int eb = t >> 6;  // 0..3
            int k = k0 + kl;
            #pragma unroll
            for (int p = 0; p < 16; ++p) {
                int e = eb + p * 4;
                float v;
                if (k < 128)      v = nf[(size_t)sidx[e] * D + k];
                else if (k < 256) v = nf[(size_t)didx[e] * D + (k - 128)];
                else              v = ef[(size_t)(e0 + e) * D + (k - 256)];
                zt[kl][e] = v;
            }
        }
        // stage w chunk: 64 k x 128 c
        {
            int c = t & 127;
            int kr = t >> 7;  // 0..1
            #pragma unroll
            for (int p = 0; p < 32; ++p) {
                int kl2 = kr + p * 2;
                wt[kl2][c] = wp[(size_t)(k0 + kl2) * D + c];
            }
        }
        __syncthreads();
        #pragma unroll 4
        for (int k = 0; k < 64; ++k) {
            float4 a4 = *(const float4*)(&zt[k][te * 4]);
            float4 wA = *(const float4*)(&wt[k][tc * 8]);
            float4 wB = *(const float4*)(&wt[k][tc * 8 + 4]);
            float av[4] = {a4.x, a4.y, a4.z, a4.w};
            float wv[8] = {wA.x, wA.y, wA.z, wA.w, wB.x, wB.y, wB.z, wB.w};
            #pragma unroll
            for (int i = 0; i < 4; ++i)
                #pragma unroll
                for (int j = 0; j < 8; ++j)
                    acc[i][j] = fmaf(av[i], wv[j], acc[i][j]);
        }
        __syncthreads();
    }

    // epilogue: bias + relu + 4-way scatter atomics
    int cb = tc * 8;
    #pragma unroll
    for (int i = 0; i < 4; ++i) {
        int el = te * 4 + i;
        int dn = didx[el];
        size_t base = (size_t)dn * D + cb;
        #pragma unroll
        for (int j = 0; j < 8; ++j) {
            float v = fmaxf(acc[i][j] + bp[cb + j], 0.f);
            atomicAdd(&s1[base + j], v);
            atomicAdd(&s2[base + j], v * v);
            atomicMax((int*)&mx[base + j], __float_as_int(v));  // v >= 0
            atomicMin((int*)&mn[base + j], __float_as_int(v));
        }
    }
}

// ---------------- finalize aggregators in-place + per-node scalers ----------------
__global__ void k_finalize(float* s1, float* s2, float* mx, float* mn,
                           const float* __restrict__ deg, float* scal) {
    size_t idx = (size_t)blockIdx.x * blockDim.x + threadIdx.x;
    if (idx >= (size_t)N_NODES * D) return;
    int n = (int)(idx >> 7);
    int c = (int)(idx & 127);
    float dg = deg[n];
    float ds = fmaxf(dg, 1.f);
    float m  = s1[idx] / ds;
    float var = fmaxf(s2[idx] / ds - m * m, 0.f);
    float sd  = sqrtf(var + EPS);
    bool nb = dg > 0.f;
    s1[idx] = m;                      // mean
    mx[idx] = nb ? mx[idx] : 0.f;     // max (masked)
    mn[idx] = nb ? mn[idx] : 0.f;     // min (masked)
    s2[idx] = sd;                     // std (NOT masked, matches ref)
    if (c == 0) {
        float logd = logf(dg + 1.f);
        scal[2 * n]     = logd / AVG_D_LOG;
        scal[2 * n + 1] = AVG_D_LOG / fmaxf(logd, EPS);
    }
}

// ---------------- posttrans1: h1 = relu(h @ w_post1 + b1), h staged virtually ----------------
__global__ __launch_bounds__(256) void k_post1(
    const float* __restrict__ nf,
    const float* __restrict__ amean, const float* __restrict__ amax,
    const float* __restrict__ amin,  const float* __restrict__ astd,
    const float* __restrict__ scal,
    const float* __restrict__ w1, const float* __restrict__ b1,
    float* __restrict__ h1)
{
    __shared__ float at[64][68];
    __shared__ float wt[64][128];
    __shared__ float samp[64], satt[64];

    int t = threadIdx.x;
    int n0 = blockIdx.x * 64;
    if (t < 64) {
        int n = n0 + t;
        samp[t] = (n < N_NODES) ? scal[2 * n] : 0.f;
        satt[t] = (n < N_NODES) ? scal[2 * n + 1] : 0.f;
    }
    __syncthreads();

    int tc = t & 15, te = t >> 4;
    float acc[4][8] = {};

    for (int chunk = 0; chunk < 26; ++chunk) {
        int f0 = chunk * 64;
        int r  = (f0 < 128) ? 0 : ((f0 < 640) ? 1 : ((f0 < 1152) ? 2 : 3));
        int j0 = f0 - (r == 0 ? 0 : (r == 1 ? 128 : (r == 2 ? 640 : 1152)));
        const float* base;
        if (r == 0) base = nf;
        else {
            int b = j0 >> 7;
            base = (b == 0) ? amean : (b == 1) ? amax : (b == 2) ? amin : astd;
        }
        int ch0 = j0 & 127;

        {
            int kl = t & 63, nb = t >> 6;
            #pragma unroll
            for (int p = 0; p < 16; ++p) {
                int il = nb + p * 4;
                int n = n0 + il;
                float v = 0.f;
                if (n < N_NODES) {
                    v = base[(size_t)n * D + ch0 + kl];
                    if (r == 2) v *= samp[il];
                    else if (r == 3) v *= satt[il];
                }
                at[kl][il] = v;
            }
        }
        {
            int c = t & 127, kr = t >> 7;
            #pragma unroll
            for (int p = 0; p < 32; ++p) {
                int kl2 = kr + p * 2;
                wt[kl2][c] = w1[(size_t)(f0 + kl2) * D + c];
            }
        }
        __syncthreads();
        #pragma unroll 4
        for (int k = 0; k < 64; ++k) {
            float4 a4 = *(const float4*)(&at[k][te * 4]);
            float4 wA = *(const float4*)(&wt[k][tc * 8]);
            float4 wB = *(const float4*)(&wt[k][tc * 8 + 4]);
            float av[4] = {a4.x, a4.y, a4.z, a4.w};
            float wv[8] = {wA.x, wA.y, wA.z, wA.w, wB.x, wB.y, wB.z, wB.w};
            #pragma unroll
            for (int i = 0; i < 4; ++i)
                #pragma unroll
                for (int j = 0; j < 8; ++j)
                    acc[i][j] = fmaf(av[i], wv[j], acc[i][j]);
        }
        __syncthreads();
    }

    int cb = tc * 8;
    #pragma unroll
    for (int i = 0; i < 4; ++i) {
        int n = n0 + te * 4 + i;
        if (n >= N_NODES) break;
        #pragma unroll
        for (int j = 0; j < 8; ++j) {
            float v = fmaxf(acc[i][j] + b1[cb + j], 0.f);
            h1[(size_t)n * D + cb + j] = v;
        }
    }
}

// ---------------- posttrans2: out = h1 @ w_post2 + b2 + nf ----------------
__global__ __launch_bounds__(256) void k_post2(
    const float* __restrict__ h1, const float* __restrict__ w2,
    const float* __restrict__ b2, const float* __restrict__ nf,
    float* __restrict__ out)
{
    __shared__ float at[64][68];
    __shared__ float wt[64][128];

    int t = threadIdx.x;
    int n0 = blockIdx.x * 64;
    int tc = t & 15, te = t >> 4;
    float acc[4][8] = {};

    for (int chunk = 0; chunk < 2; ++chunk) {
        int f0 = chunk * 64;
        {
            int kl = t & 63, nb = t >> 6;
            #pragma unroll
            for (int p = 0; p < 16; ++p) {
                int il = nb + p * 4;
                int n = n0 + il;
                at[kl][il] = (n < N_NODES) ? h1[(size_t)n * D + f0 + kl] : 0.f;
            }
        }
        {
            int c = t & 127, kr = t >> 7;
            #pragma unroll
            for (int p = 0; p < 32; ++p) {
                int kl2 = kr + p * 2;
                wt[kl2][c] = w2[(size_t)(f0 + kl2) * D + c];
            }
        }
        __syncthreads();
        #pragma unroll 4
        for (int k = 0; k < 64; ++k) {
            float4 a4 = *(const float4*)(&at[k][te * 4]);
            float4 wA = *(const float4*)(&wt[k][tc * 8]);
            float4 wB = *(const float4*)(&wt[k][tc * 8 + 4]);
            float av[4] = {a4.x, a4.y, a4.z, a4.w};
            float wv[8] = {wA.x, wA.y, wA.z, wA.w, wB.x, wB.y, wB.z, wB.w};
            #pragma unroll
            for (int i = 0; i < 4; ++i)
                #pragma unroll
                for (int j = 0; j < 8; ++j)
                    acc[i][j] = fmaf(av[i], wv[j], acc[i][j]);
        }
        __syncthreads();
    }

    int cb = tc * 8;
    #pragma unroll
    for (int i = 0; i < 4; ++i) {
        int n = n0 + te * 4 + i;
        if (n >= N_NODES) break;
        #pragma unroll
        for (int j = 0; j < 8; ++j) {
            out[(size_t)n * D + cb + j] = acc[i][j] + b2[cb + j] + nf[(size_t)n * D + cb + j];
        }
    }
}

extern "C" void kernel_launch(void* const* d_in, const int* in_sizes, int n_in,
                              void* d_out, int out_size, void* d_ws, size_t ws_size,
                              hipStream_t stream) {
    const float* nf = (const float*)d_in[0];
    const float* ef = (const float*)d_in[1];
    const float* wp = (const float*)d_in[2];
    const float* bp = (const float*)d_in[3];
    const float* w1 = (const float*)d_in[4];
    const float* b1 = (const float*)d_in[5];
    const float* w2 = (const float*)d_in[6];
    const float* b2 = (const float*)d_in[7];
    const int* src  = (const int*)d_in[8];
    const int* dst  = (const int*)d_in[9];
    float* out = (float*)d_out;

    const size_t ND = (size_t)N_NODES * D;  // 6.4M
    float* ws   = (float*)d_ws;
    float* deg  = ws;                // N (padded to 50048)
    float* s1   = ws + 50048;        // ND  -> mean
    float* s2   = s1 + ND;           // ND  -> std
    float* mx   = s2 + ND;           // ND  -> max
    float* mn   = mx + ND;           // ND  -> min
    float* scal = mn + ND;           // 2N (padded to 100096)
    float* h1   = scal + 100096;     // ND

    hipLaunchKernelGGL(k_init, dim3(2048), dim3(256), 0, stream, deg, s1, s2, mx, mn);
    hipLaunchKernelGGL(k_pretrans, dim3(N_EDGES / 64), dim3(256), 0, stream,
                       nf, ef, wp, bp, src, dst, s1, s2, mx, mn, deg);
    hipLaunchKernelGGL(k_finalize, dim3((unsigned)((ND + 255) / 256)), dim3(256), 0, stream,
                       s1, s2, mx, mn, deg, scal);
    hipLaunchKernelGGL(k_post1, dim3((N_NODES + 63) / 64), dim3(256), 0, stream,
                       nf, s1, mx, mn, s2, scal, w1, b1, h1);
    hipLaunchKernelGGL(k_post2, dim3((N_NODES + 63) / 64), dim3(256), 0, stream,
                       h1, w2, b2, nf, out);
}

// Round 2
// 1983.685 us; speedup vs baseline: 5.0566x; 5.0566x over previous
//
#include <hip/hip_runtime.h>
#include <math.h>

#define N_NODES 50000
#define N_EDGES 800000
#define D 128
#define AVG_D_LOG 2.833213344056216f  /* log(17.0) */
#define EPS 1e-5f

// ---------------- init: zero accumulators, +inf for min, zero hist ----------------
__global__ void k_init(int* hist, float* s1, float* s2, float* mx, float* mn) {
    size_t stride = (size_t)gridDim.x * blockDim.x;
    size_t i0 = (size_t)blockIdx.x * blockDim.x + threadIdx.x;
    const size_t ND = (size_t)N_NODES * D;
    for (size_t t = i0; t < ND; t += stride) {
        s1[t] = 0.f; s2[t] = 0.f; mx[t] = 0.f;
        ((int*)mn)[t] = 0x7f800000;  // +inf
    }
    for (size_t t = i0; t < N_NODES; t += stride) hist[t] = 0;
}

// ---------------- CSR build ----------------
__global__ void k_hist(const int* __restrict__ dst, int* hist) {
    int e = blockIdx.x * blockDim.x + threadIdx.x;
    if (e < N_EDGES) atomicAdd(&hist[dst[e]], 1);
}

// single-block exclusive scan of hist -> cursor (row starts)
__global__ void k_scan(const int* __restrict__ hist, int* cursor) {
    __shared__ int part[256];
    __shared__ int base_s[256];
    int t = threadIdx.x;
    const int chunk = (N_NODES + 255) / 256;
    int lo = t * chunk;
    int hi = lo + chunk; if (hi > N_NODES) hi = N_NODES;
    int s = 0;
    for (int i = lo; i < hi; ++i) s += hist[i];
    part[t] = s;
    __syncthreads();
    if (t == 0) {
        int run = 0;
        for (int i = 0; i < 256; ++i) { base_s[i] = run; run += part[i]; }
    }
    __syncthreads();
    int run = base_s[t];
    for (int i = lo; i < hi; ++i) { cursor[i] = run; run += hist[i]; }
}

__global__ void k_scatter(const int* __restrict__ dst, int* cursor, int* perm) {
    int e = blockIdx.x * blockDim.x + threadIdx.x;
    if (e < N_EDGES) {
        int pos = atomicAdd(&cursor[dst[e]], 1);
        perm[pos] = e;
    }
}

// ---------------- pretrans edge MLP + fused segmented scatter ----------------
// tile: 64 dst-sorted edges x 128 out, K=384 in 6 chunks of 64. 256 threads.
__global__ __launch_bounds__(256) void k_pretrans(
    const float* __restrict__ nf, const float* __restrict__ ef,
    const float* __restrict__ wp, const float* __restrict__ bp,
    const int* __restrict__ src, const int* __restrict__ dst,
    const int* __restrict__ perm,
    float* s1, float* s2, float* mx, float* mn)
{
    __shared__ float zt[64][68];   // [k_local][edge]
    __shared__ float wt[64][128];  // GEMM: [k_local][channel]; epilogue: msg[edge][channel]
    __shared__ int pidx[64], sidx[64], didx[64];
    __shared__ int seg_start[65], seg_dst[64];
    __shared__ int nseg_s;

    int t = threadIdx.x;
    int e0 = blockIdx.x * 64;
    if (t < 64) {
        int pe = perm[e0 + t];
        pidx[t] = pe; sidx[t] = src[pe]; didx[t] = dst[pe];
    }
    __syncthreads();

    int tc = t & 15;   // channel group: channels tc*8..tc*8+7
    int te = t >> 4;   // edge group:    edges te*4..te*4+3
    float acc[4][8] = {};

    for (int chunk = 0; chunk < 6; ++chunk) {
        int k0 = chunk * 64;
        {
            int kl = t & 63;
            int eb = t >> 6;  // 0..3
            int k = k0 + kl;
            #pragma unroll
            for (int p = 0; p < 16; ++p) {
                int e = eb + p * 4;
                float v;
                if (k < 128)      v = nf[(size_t)sidx[e] * D + k];
                else if (k < 256) v = nf[(size_t)didx[e] * D + (k - 128)];
                else              v = ef[(size_t)pidx[e] * D + (k - 256)];
                zt[kl][e] = v;
            }
        }
        {
            int c = t & 127;
            int kr = t >> 7;  // 0..1
            #pragma unroll
            for (int p = 0; p < 32; ++p) {
                int kl2 = kr + p * 2;
                wt[kl2][c] = wp[(size_t)(k0 + kl2) * D + c];
            }
        }
        __syncthreads();
        #pragma unroll 4
        for (int k = 0; k < 64; ++k) {
            float4 a4 = *(const float4*)(&zt[k][te * 4]);
            float4 wA = *(const float4*)(&wt[k][tc * 8]);
            float4 wB = *(const float4*)(&wt[k][tc * 8 + 4]);
            float av[4] = {a4.x, a4.y, a4.z, a4.w};
            float wv[8] = {wA.x, wA.y, wA.z, wA.w, wB.x, wB.y, wB.z, wB.w};
            #pragma unroll
            for (int i = 0; i < 4; ++i)
                #pragma unroll
                for (int j = 0; j < 8; ++j)
                    acc[i][j] = fmaf(av[i], wv[j], acc[i][j]);
        }
        __syncthreads();
    }

    // ---- epilogue: bias+relu into LDS as msg[edge][ch] ----
    int cb = tc * 8;
    #pragma unroll
    for (int i = 0; i < 4; ++i) {
        int el = te * 4 + i;
        #pragma unroll
        for (int j = 0; j < 8; ++j)
            wt[el][cb + j] = fmaxf(acc[i][j] + bp[cb + j], 0.f);
    }
    // segment boundaries (dst-sorted tile)
    if (t == 0) {
        int ns = 0;
        for (int e = 0; e < 64; ++e) {
            if (e == 0 || didx[e] != didx[e - 1]) {
                seg_dst[ns] = didx[e]; seg_start[ns] = e; ++ns;
            }
        }
        seg_start[ns] = 64; nseg_s = ns;
    }
    __syncthreads();
    int nseg = nseg_s;
    // segmented reduce: (segment, channel) pairs across 256 threads
    for (int idx = t; idx < nseg * D; idx += 256) {
        int sg = idx >> 7, c = idx & 127;
        int eb = seg_start[sg], ee = seg_start[sg + 1];
        float s = 0.f, q = 0.f, vmax = 0.f, vmin = __int_as_float(0x7f800000);
        for (int e = eb; e < ee; ++e) {
            float v = wt[e][c];
            s += v; q += v * v;
            vmax = fmaxf(vmax, v); vmin = fminf(vmin, v);
        }
        size_t base = (size_t)seg_dst[sg] * D + c;
        bool boundary = (sg == 0) || (sg == nseg - 1);
        if (boundary) {
            atomicAdd(&s1[base], s);
            atomicAdd(&s2[base], q);
            atomicMax((int*)&mx[base], __float_as_int(vmax));  // all values >= 0
            atomicMin((int*)&mn[base], __float_as_int(vmin));
        } else {
            s1[base] = s; s2[base] = q; mx[base] = vmax; mn[base] = vmin;
        }
    }
}

// ---------------- finalize aggregators in-place + per-node scalers ----------------
__global__ void k_finalize(float* s1, float* s2, float* mx, float* mn,
                           const int* __restrict__ hist, float* scal) {
    size_t idx = (size_t)blockIdx.x * blockDim.x + threadIdx.x;
    if (idx >= (size_t)N_NODES * D) return;
    int n = (int)(idx >> 7);
    int c = (int)(idx & 127);
    float dg = (float)hist[n];
    float ds = fmaxf(dg, 1.f);
    float m  = s1[idx] / ds;
    float var = fmaxf(s2[idx] / ds - m * m, 0.f);
    float sd  = sqrtf(var + EPS);
    bool nb = dg > 0.f;
    s1[idx] = m;                      // mean
    mx[idx] = nb ? mx[idx] : 0.f;     // max (masked)
    mn[idx] = nb ? mn[idx] : 0.f;     // min (masked)
    s2[idx] = sd;                     // std (NOT masked, matches ref)
    if (c == 0) {
        float logd = logf(dg + 1.f);
        scal[2 * n]     = logd / AVG_D_LOG;
        scal[2 * n + 1] = AVG_D_LOG / fmaxf(logd, EPS);
    }
}

// ---------------- posttrans1: h1 = relu(h @ w_post1 + b1), h staged virtually ----------------
__global__ __launch_bounds__(256) void k_post1(
    const float* __restrict__ nf,
    const float* __restrict__ amean, const float* __restrict__ amax,
    const float* __restrict__ amin,  const float* __restrict__ astd,
    const float* __restrict__ scal,
    const float* __restrict__ w1, const float* __restrict__ b1,
    float* __restrict__ h1)
{
    __shared__ float at[64][68];
    __shared__ float wt[64][128];
    __shared__ float samp[64], satt[64];

    int t = threadIdx.x;
    int n0 = blockIdx.x * 64;
    if (t < 64) {
        int n = n0 + t;
        samp[t] = (n < N_NODES) ? scal[2 * n] : 0.f;
        satt[t] = (n < N_NODES) ? scal[2 * n + 1] : 0.f;
    }
    __syncthreads();

    int tc = t & 15, te = t >> 4;
    float acc[4][8] = {};

    for (int chunk = 0; chunk < 26; ++chunk) {
        int f0 = chunk * 64;
        int r  = (f0 < 128) ? 0 : ((f0 < 640) ? 1 : ((f0 < 1152) ? 2 : 3));
        int j0 = f0 - (r == 0 ? 0 : (r == 1 ? 128 : (r == 2 ? 640 : 1152)));
        const float* base;
        if (r == 0) base = nf;
        else {
            int b = j0 >> 7;
            base = (b == 0) ? amean : (b == 1) ? amax : (b == 2) ? amin : astd;
        }
        int ch0 = j0 & 127;

        {
            int kl = t & 63, nb = t >> 6;
            #pragma unroll
            for (int p = 0; p < 16; ++p) {
                int il = nb + p * 4;
                int n = n0 + il;
                float v = 0.f;
                if (n < N_NODES) {
                    v = base[(size_t)n * D + ch0 + kl];
                    if (r == 2) v *= samp[il];
                    else if (r == 3) v *= satt[il];
                }
                at[kl][il] = v;
            }
        }
        {
            int c = t & 127, kr = t >> 7;
            #pragma unroll
            for (int p = 0; p < 32; ++p) {
                int kl2 = kr + p * 2;
                wt[kl2][c] = w1[(size_t)(f0 + kl2) * D + c];
            }
        }
        __syncthreads();
        #pragma unroll 4
        for (int k = 0; k < 64; ++k) {
            float4 a4 = *(const float4*)(&at[k][te * 4]);
            float4 wA = *(const float4*)(&wt[k][tc * 8]);
            float4 wB = *(const float4*)(&wt[k][tc * 8 + 4]);
            float av[4] = {a4.x, a4.y, a4.z, a4.w};
            float wv[8] = {wA.x, wA.y, wA.z, wA.w, wB.x, wB.y, wB.z, wB.w};
            #pragma unroll
            for (int i = 0; i < 4; ++i)
                #pragma unroll
                for (int j = 0; j < 8; ++j)
                    acc[i][j] = fmaf(av[i], wv[j], acc[i][j]);
        }
        __syncthreads();
    }

    int cb = tc * 8;
    #pragma unroll
    for (int i = 0; i < 4; ++i) {
        int n = n0 + te * 4 + i;
        if (n >= N_NODES) break;
        #pragma unroll
        for (int j = 0; j < 8; ++j) {
            float v = fmaxf(acc[i][j] + b1[cb + j], 0.f);
            h1[(size_t)n * D + cb + j] = v;
        }
    }
}

// ---------------- posttrans2: out = h1 @ w_post2 + b2 + nf ----------------
__global__ __launch_bounds__(256) void k_post2(
    const float* __restrict__ h1, const float* __restrict__ w2,
    const float* __restrict__ b2, const float* __restrict__ nf,
    float* __restrict__ out)
{
    __shared__ float at[64][68];
    __shared__ float wt[64][128];

    int t = threadIdx.x;
    int n0 = blockIdx.x * 64;
    int tc = t & 15, te = t >> 4;
    float acc[4][8] = {};

    for (int chunk = 0; chunk < 2; ++chunk) {
        int f0 = chunk * 64;
        {
            int kl = t & 63, nb = t >> 6;
            #pragma unroll
            for (int p = 0; p < 16; ++p) {
                int il = nb + p * 4;
                int n = n0 + il;
                at[kl][il] = (n < N_NODES) ? h1[(size_t)n * D + f0 + kl] : 0.f;
            }
        }
        {
            int c = t & 127, kr = t >> 7;
            #pragma unroll
            for (int p = 0; p < 32; ++p) {
                int kl2 = kr + p * 2;
                wt[kl2][c] = w2[(size_t)(f0 + kl2) * D + c];
            }
        }
        __syncthreads();
        #pragma unroll 4
        for (int k = 0; k < 64; ++k) {
            float4 a4 = *(const float4*)(&at[k][te * 4]);
            float4 wA = *(const float4*)(&wt[k][tc * 8]);
            float4 wB = *(const float4*)(&wt[k][tc * 8 + 4]);
            float av[4] = {a4.x, a4.y, a4.z, a4.w};
            float wv[8] = {wA.x, wA.y, wA.z, wA.w, wB.x, wB.y, wB.z, wB.w};
            #pragma unroll
            for (int i = 0; i < 4; ++i)
                #pragma unroll
                for (int j = 0; j < 8; ++j)
                    acc[i][j] = fmaf(av[i], wv[j], acc[i][j]);
        }
        __syncthreads();
    }

    int cb = tc * 8;
    #pragma unroll
    for (int i = 0; i < 4; ++i) {
        int n = n0 + te * 4 + i;
        if (n >= N_NODES) break;
        #pragma unroll
        for (int j = 0; j < 8; ++j) {
            out[(size_t)n * D + cb + j] = acc[i][j] + b2[cb + j] + nf[(size_t)n * D + cb + j];
        }
    }
}

extern "C" void kernel_launch(void* const* d_in, const int* in_sizes, int n_in,
                              void* d_out, int out_size, void* d_ws, size_t ws_size,
                              hipStream_t stream) {
    const float* nf = (const float*)d_in[0];
    const float* ef = (const float*)d_in[1];
    const float* wp = (const float*)d_in[2];
    const float* bp = (const float*)d_in[3];
    const float* w1 = (const float*)d_in[4];
    const float* b1 = (const float*)d_in[5];
    const float* w2 = (const float*)d_in[6];
    const float* b2 = (const float*)d_in[7];
    const int* src  = (const int*)d_in[8];
    const int* dst  = (const int*)d_in[9];
    float* out = (float*)d_out;

    const size_t ND = (size_t)N_NODES * D;  // 6.4M
    float* ws    = (float*)d_ws;
    int*   hist  = (int*)ws;                 // N (padded 50048)
    int*   cursor= hist + 50048;             // N (padded 50048)
    int*   perm  = cursor + 50048;           // E (800000)
    float* s1    = (float*)(perm + N_EDGES); // ND -> mean
    float* s2    = s1 + ND;                  // ND -> std
    float* mx    = s2 + ND;                  // ND -> max
    float* mn    = mx + ND;                  // ND -> min
    float* scal  = mn + ND;                  // 2N (padded 100096)
    float* h1    = scal + 100096;            // ND

    hipLaunchKernelGGL(k_init, dim3(2048), dim3(256), 0, stream, hist, s1, s2, mx, mn);
    hipLaunchKernelGGL(k_hist, dim3((N_EDGES + 255) / 256), dim3(256), 0, stream, dst, hist);
    hipLaunchKernelGGL(k_scan, dim3(1), dim3(256), 0, stream, hist, cursor);
    hipLaunchKernelGGL(k_scatter, dim3((N_EDGES + 255) / 256), dim3(256), 0, stream, dst, cursor, perm);
    hipLaunchKernelGGL(k_pretrans, dim3(N_EDGES / 64), dim3(256), 0, stream,
                       nf, ef, wp, bp, src, dst, perm, s1, s2, mx, mn);
    hipLaunchKernelGGL(k_finalize, dim3((unsigned)((ND + 255) / 256)), dim3(256), 0, stream,
                       s1, s2, mx, mn, hist, scal);
    hipLaunchKernelGGL(k_post1, dim3((N_NODES + 63) / 64), dim3(256), 0, stream,
                       nf, s1, mx, mn, s2, scal, w1, b1, h1);
    hipLaunchKernelGGL(k_post2, dim3((N_NODES + 63) / 64), dim3(256), 0, stream,
                       h1, w2, b2, nf, out);
}

// Round 3
// 1130.896 us; speedup vs baseline: 8.8696x; 1.7541x over previous
//
#include <hip/hip_runtime.h>
#include <math.h>

#define N_NODES 50000
#define N_EDGES 800000
#define D 128
#define AVG_D_LOG 2.833213344056216f  /* log(17.0) */
#define EPS 1e-5f

typedef __attribute__((ext_vector_type(8))) short bf16x8;
typedef __attribute__((ext_vector_type(4))) float f32x4;

__device__ __forceinline__ unsigned short f2bf(float x) {
    unsigned u = __float_as_uint(x);
    u += 0x7fffu + ((u >> 16) & 1u);
    return (unsigned short)(u >> 16);
}

// ---------------- init: zero accumulators, +inf for min, zero hist ----------------
__global__ void k_init(int* hist, float* s1, float* s2, float* mx, float* mn) {
    size_t stride = (size_t)gridDim.x * blockDim.x;
    size_t i0 = (size_t)blockIdx.x * blockDim.x + threadIdx.x;
    const size_t ND = (size_t)N_NODES * D;
    for (size_t t = i0; t < ND; t += stride) {
        s1[t] = 0.f; s2[t] = 0.f; mx[t] = 0.f;
        ((int*)mn)[t] = 0x7f800000;  // +inf
    }
    for (size_t t = i0; t < N_NODES; t += stride) hist[t] = 0;
}

// ---------------- CSR build ----------------
__global__ void k_hist(const int* __restrict__ dst, int* hist) {
    int e = blockIdx.x * blockDim.x + threadIdx.x;
    if (e < N_EDGES) atomicAdd(&hist[dst[e]], 1);
}

__global__ void k_scan(const int* __restrict__ hist, int* cursor) {
    __shared__ int part[256];
    __shared__ int base_s[256];
    int t = threadIdx.x;
    const int chunk = (N_NODES + 255) / 256;
    int lo = t * chunk;
    int hi = lo + chunk; if (hi > N_NODES) hi = N_NODES;
    int s = 0;
    for (int i = lo; i < hi; ++i) s += hist[i];
    part[t] = s;
    __syncthreads();
    if (t == 0) {
        int run = 0;
        for (int i = 0; i < 256; ++i) { base_s[i] = run; run += part[i]; }
    }
    __syncthreads();
    int run = base_s[t];
    for (int i = lo; i < hi; ++i) { cursor[i] = run; run += hist[i]; }
}

__global__ void k_scatter(const int* __restrict__ dst, int* cursor, int* perm) {
    int e = blockIdx.x * blockDim.x + threadIdx.x;
    if (e < N_EDGES) {
        int pos = atomicAdd(&cursor[dst[e]], 1);
        perm[pos] = e;
    }
}

// ---------------- one-time: w_pre [384][128] fp32 -> wpT [128][384] bf16 ----------------
__global__ void k_prepw(const float* __restrict__ wp, unsigned short* __restrict__ wpT) {
    int idx = blockIdx.x * blockDim.x + threadIdx.x;
    if (idx >= 384 * D) return;
    int k = idx >> 7, c = idx & 127;
    wpT[(size_t)c * 384 + k] = f2bf(wp[idx]);
}

// ---------------- pretrans edge MLP (bf16 MFMA) + fused segmented scatter ----------------
// tile: 64 dst-sorted edges x 128 out channels, K=384 in 3 chunks of 128.
// D[c][e] = W^T[c][k] * z^T[k][e]; 4 waves, wave w: channels w*32..w*32+31, all 64 edges.
__global__ __launch_bounds__(256) void k_pretrans(
    const float* __restrict__ nf, const float* __restrict__ ef,
    const unsigned short* __restrict__ wpT, const float* __restrict__ bp,
    const int* __restrict__ src, const int* __restrict__ dst,
    const int* __restrict__ perm,
    float* s1, float* s2, float* mx, float* mn)
{
    __shared__ __align__(16) char smem[49152]; // awt 32KB + zt 16KB | msgT 33.3KB
    unsigned short* awt = (unsigned short*)smem;            // [128][128] bf16, swizzled
    float* msgT = (float*)smem;                             // [128][65] fp32 (epilogue)
    __shared__ int pidx[64], sidx[64], didx[64];
    __shared__ int seg_start[65], seg_dst[64];
    __shared__ int nseg_s;
    __shared__ float sb[128];

    int t = threadIdx.x;
    int e0 = blockIdx.x * 64;
    if (t < 64) {
        int pe = perm[e0 + t];
        pidx[t] = pe; sidx[t] = src[pe]; didx[t] = dst[pe];
    }
    if (t < 128) sb[t] = bp[t];
    __syncthreads();

    int w  = t >> 6;   // wave 0..3
    int l  = t & 63;
    int lr = l & 15;   // fragment row(A)/col(B) index
    int lg = l >> 4;   // k-octet group 0..3

    f32x4 acc[2][4];
    #pragma unroll
    for (int i = 0; i < 2; ++i)
        #pragma unroll
        for (int j = 0; j < 4; ++j) acc[i][j] = (f32x4){0.f, 0.f, 0.f, 0.f};

    for (int chunk = 0; chunk < 3; ++chunk) {
        // ---- stage W chunk: awt[c][0..127] bf16, byte = c*256 + ((kc*2) ^ ((c&7)<<4))
        #pragma unroll
        for (int p = 0; p < 8; ++p) {
            int v  = t + 256 * p;       // 0..2047
            int c  = v >> 4;
            int kq = (v & 15) * 8;      // bf16 idx, 16B granule
            uint4 wv = *(const uint4*)(wpT + (size_t)c * 384 + chunk * 128 + kq);
            int byte = c * 256 + ((kq * 2) ^ ((c & 7) << 4));
            *(uint4*)(smem + byte) = wv;
        }
        // ---- stage z chunk: zt[e][0..127] bf16 at smem+32768, same swizzle by e
        #pragma unroll
        for (int p = 0; p < 8; ++p) {
            int v  = t + 256 * p;       // 0..2047
            int e  = v >> 5;
            int kq = (v & 31) * 4;      // fp32 idx, float4 granule
            const float* srcp;
            if (chunk == 0)      srcp = nf + (size_t)sidx[e] * D + kq;
            else if (chunk == 1) srcp = nf + (size_t)didx[e] * D + kq;
            else                 srcp = ef + (size_t)pidx[e] * D + kq;
            float4 fv = *(const float4*)srcp;
            ushort4 hv = { f2bf(fv.x), f2bf(fv.y), f2bf(fv.z), f2bf(fv.w) };
            int byte = 32768 + e * 256 + ((kq * 2) ^ ((e & 7) << 4));
            *(ushort4*)(smem + byte) = hv;  // 8B store
        }
        __syncthreads();
        // ---- 4 K-steps of 32
        #pragma unroll
        for (int ks = 0; ks < 4; ++ks) {
            bf16x8 afr[2], bfr[4];
            int kb = (ks * 32 + lg * 8) * 2;   // byte offset of lane's k-octet
            #pragma unroll
            for (int cf = 0; cf < 2; ++cf) {
                int c = w * 32 + cf * 16 + lr;
                afr[cf] = *(const bf16x8*)(smem + c * 256 + (kb ^ ((c & 7) << 4)));
            }
            #pragma unroll
            for (int eb = 0; eb < 4; ++eb) {
                int e = eb * 16 + lr;
                bfr[eb] = *(const bf16x8*)(smem + 32768 + e * 256 + (kb ^ ((e & 7) << 4)));
            }
            #pragma unroll
            for (int cf = 0; cf < 2; ++cf)
                #pragma unroll
                for (int eb = 0; eb < 4; ++eb)
                    acc[cf][eb] = __builtin_amdgcn_mfma_f32_16x16x32_bf16(
                        afr[cf], bfr[eb], acc[cf][eb], 0, 0, 0);
        }
        __syncthreads();
    }

    // ---- epilogue: bias+relu -> msgT[c][e] (LDS reuse; row stride 65 fp32) ----
    #pragma unroll
    for (int cf = 0; cf < 2; ++cf)
        #pragma unroll
        for (int eb = 0; eb < 4; ++eb)
            #pragma unroll
            for (int r = 0; r < 4; ++r) {
                int c = w * 32 + cf * 16 + lg * 4 + r;   // D row = (lane>>4)*4+reg
                int e = eb * 16 + lr;                    // D col = lane&15
                msgT[c * 65 + e] = fmaxf(acc[cf][eb][r] + sb[c], 0.f);
            }
    if (t == 0) {
        int ns = 0;
        for (int e = 0; e < 64; ++e) {
            if (e == 0 || didx[e] != didx[e - 1]) { seg_dst[ns] = didx[e]; seg_start[ns] = e; ++ns; }
        }
        seg_start[ns] = 64; nseg_s = ns;
    }
    __syncthreads();
    int nseg = nseg_s;
    for (int idx = t; idx < nseg * D; idx += 256) {
        int sg = idx >> 7, c = idx & 127;
        int eb2 = seg_start[sg], ee = seg_start[sg + 1];
        float s = 0.f, q = 0.f, vmax = 0.f, vmin = __int_as_float(0x7f800000);
        for (int e = eb2; e < ee; ++e) {
            float v = msgT[c * 65 + e];
            s += v; q += v * v;
            vmax = fmaxf(vmax, v); vmin = fminf(vmin, v);
        }
        size_t base = (size_t)seg_dst[sg] * D + c;
        bool boundary = (sg == 0) || (sg == nseg - 1);
        if (boundary) {
            atomicAdd(&s1[base], s);
            atomicAdd(&s2[base], q);
            atomicMax((int*)&mx[base], __float_as_int(vmax));  // msg >= 0
            atomicMin((int*)&mn[base], __float_as_int(vmin));
        } else {
            s1[base] = s; s2[base] = q; mx[base] = vmax; mn[base] = vmin;
        }
    }
}

// ---------------- finalize aggregators in-place + per-node scalers ----------------
__global__ void k_finalize(float* s1, float* s2, float* mx, float* mn,
                           const int* __restrict__ hist, float* scal) {
    size_t idx = (size_t)blockIdx.x * blockDim.x + threadIdx.x;
    if (idx >= (size_t)N_NODES * D) return;
    int n = (int)(idx >> 7);
    int c = (int)(idx & 127);
    float dg = (float)hist[n];
    float ds = fmaxf(dg, 1.f);
    float m  = s1[idx] / ds;
    float var = fmaxf(s2[idx] / ds - m * m, 0.f);
    float sd  = sqrtf(var + EPS);
    bool nb = dg > 0.f;
    s1[idx] = m;
    mx[idx] = nb ? mx[idx] : 0.f;
    mn[idx] = nb ? mn[idx] : 0.f;
    s2[idx] = sd;
    if (c == 0) {
        float logd = logf(dg + 1.f);
        scal[2 * n]     = logd / AVG_D_LOG;
        scal[2 * n + 1] = AVG_D_LOG / fmaxf(logd, EPS);
    }
}

// ---------------- posttrans1 (fp32): h1 = relu(h @ w_post1 + b1) ----------------
__global__ __launch_bounds__(256) void k_post1(
    const float* __restrict__ nf,
    const float* __restrict__ amean, const float* __restrict__ amax,
    const float* __restrict__ amin,  const float* __restrict__ astd,
    const float* __restrict__ scal,
    const float* __restrict__ w1, const float* __restrict__ b1,
    float* __restrict__ h1)
{
    __shared__ float at[64][68];
    __shared__ float wt[64][128];
    __shared__ float samp[64], satt[64];

    int t = threadIdx.x;
    int n0 = blockIdx.x * 64;
    if (t < 64) {
        int n = n0 + t;
        samp[t] = (n < N_NODES) ? scal[2 * n] : 0.f;
        satt[t] = (n < N_NODES) ? scal[2 * n + 1] : 0.f;
    }
    __syncthreads();

    int tc = t & 15, te = t >> 4;
    float acc[4][8] = {};

    for (int chunk = 0; chunk < 26; ++chunk) {
        int f0 = chunk * 64;
        int r  = (f0 < 128) ? 0 : ((f0 < 640) ? 1 : ((f0 < 1152) ? 2 : 3));
        int j0 = f0 - (r == 0 ? 0 : (r == 1 ? 128 : (r == 2 ? 640 : 1152)));
        const float* base;
        if (r == 0) base = nf;
        else {
            int b = j0 >> 7;
            base = (b == 0) ? amean : (b == 1) ? amax : (b == 2) ? amin : astd;
        }
        int ch0 = j0 & 127;

        {
            int kl = t & 63, nb = t >> 6;
            #pragma unroll
            for (int p = 0; p < 16; ++p) {
                int il = nb + p * 4;
                int n = n0 + il;
                float v = 0.f;
                if (n < N_NODES) {
                    v = base[(size_t)n * D + ch0 + kl];
                    if (r == 2) v *= samp[il];
                    else if (r == 3) v *= satt[il];
                }
                at[kl][il] = v;
            }
        }
        {
            int c = t & 127, kr = t >> 7;
            #pragma unroll
            for (int p = 0; p < 32; ++p) {
                int kl2 = kr + p * 2;
                wt[kl2][c] = w1[(size_t)(f0 + kl2) * D + c];
            }
        }
        __syncthreads();
        #pragma unroll 4
        for (int k = 0; k < 64; ++k) {
            float4 a4 = *(const float4*)(&at[k][te * 4]);
            float4 wA = *(const float4*)(&wt[k][tc * 8]);
            float4 wB = *(const float4*)(&wt[k][tc * 8 + 4]);
            float av[4] = {a4.x, a4.y, a4.z, a4.w};
            float wv[8] = {wA.x, wA.y, wA.z, wA.w, wB.x, wB.y, wB.z, wB.w};
            #pragma unroll
            for (int i = 0; i < 4; ++i)
                #pragma unroll
                for (int j = 0; j < 8; ++j)
                    acc[i][j] = fmaf(av[i], wv[j], acc[i][j]);
        }
        __syncthreads();
    }

    int cb = tc * 8;
    #pragma unroll
    for (int i = 0; i < 4; ++i) {
        int n = n0 + te * 4 + i;
        if (n >= N_NODES) break;
        #pragma unroll
        for (int j = 0; j < 8; ++j) {
            float v = fmaxf(acc[i][j] + b1[cb + j], 0.f);
            h1[(size_t)n * D + cb + j] = v;
        }
    }
}

// ---------------- posttrans2: out = h1 @ w_post2 + b2 + nf ----------------
__global__ __launch_bounds__(256) void k_post2(
    const float* __restrict__ h1, const float* __restrict__ w2,
    const float* __restrict__ b2, const float* __restrict__ nf,
    float* __restrict__ out)
{
    __shared__ float at[64][68];
    __shared__ float wt[64][128];

    int t = threadIdx.x;
    int n0 = blockIdx.x * 64;
    int tc = t & 15, te = t >> 4;
    float acc[4][8] = {};

    for (int chunk = 0; chunk < 2; ++chunk) {
        int f0 = chunk * 64;
        {
            int kl = t & 63, nb = t >> 6;
            #pragma unroll
            for (int p = 0; p < 16; ++p) {
                int il = nb + p * 4;
                int n = n0 + il;
                at[kl][il] = (n < N_NODES) ? h1[(size_t)n * D + f0 + kl] : 0.f;
            }
        }
        {
            int c = t & 127, kr = t >> 7;
            #pragma unroll
            for (int p = 0; p < 32; ++p) {
                int kl2 = kr + p * 2;
                wt[kl2][c] = w2[(size_t)(f0 + kl2) * D + c];
            }
        }
        __syncthreads();
        #pragma unroll 4
        for (int k = 0; k < 64; ++k) {
            float4 a4 = *(const float4*)(&at[k][te * 4]);
            float4 wA = *(const float4*)(&wt[k][tc * 8]);
            float4 wB = *(const float4*)(&wt[k][tc * 8 + 4]);
            float av[4] = {a4.x, a4.y, a4.z, a4.w};
            float wv[8] = {wA.x, wA.y, wA.z, wA.w, wB.x, wB.y, wB.z, wB.w};
            #pragma unroll
            for (int i = 0; i < 4; ++i)
                #pragma unroll
                for (int j = 0; j < 8; ++j)
                    acc[i][j] = fmaf(av[i], wv[j], acc[i][j]);
        }
        __syncthreads();
    }

    int cb = tc * 8;
    #pragma unroll
    for (int i = 0; i < 4; ++i) {
        int n = n0 + te * 4 + i;
        if (n >= N_NODES) break;
        #pragma unroll
        for (int j = 0; j < 8; ++j) {
            out[(size_t)n * D + cb + j] = acc[i][j] + b2[cb + j] + nf[(size_t)n * D + cb + j];
        }
    }
}

extern "C" void kernel_launch(void* const* d_in, const int* in_sizes, int n_in,
                              void* d_out, int out_size, void* d_ws, size_t ws_size,
                              hipStream_t stream) {
    const float* nf = (const float*)d_in[0];
    const float* ef = (const float*)d_in[1];
    const float* wp = (const float*)d_in[2];
    const float* bp = (const float*)d_in[3];
    const float* w1 = (const float*)d_in[4];
    const float* b1 = (const float*)d_in[5];
    const float* w2 = (const float*)d_in[6];
    const float* b2 = (const float*)d_in[7];
    const int* src  = (const int*)d_in[8];
    const int* dst  = (const int*)d_in[9];
    float* out = (float*)d_out;

    const size_t ND = (size_t)N_NODES * D;  // 6.4M
    float* ws     = (float*)d_ws;
    int*   hist   = (int*)ws;                   // 50048 ints
    int*   cursor = hist + 50048;               // 50048 ints
    int*   perm   = cursor + 50048;             // 800000 ints
    unsigned short* wpT = (unsigned short*)(perm + N_EDGES);  // 49152 bf16 (16B-aligned)
    float* s1     = (float*)(wpT + 49152);      // ND -> mean
    float* s2     = s1 + ND;                    // ND -> std
    float* mx     = s2 + ND;                    // ND -> max
    float* mn     = mx + ND;                    // ND -> min
    float* scal   = mn + ND;                    // 2N (padded 100096)
    float* h1     = scal + 100096;              // ND

    hipLaunchKernelGGL(k_init, dim3(2048), dim3(256), 0, stream, hist, s1, s2, mx, mn);
    hipLaunchKernelGGL(k_hist, dim3((N_EDGES + 255) / 256), dim3(256), 0, stream, dst, hist);
    hipLaunchKernelGGL(k_scan, dim3(1), dim3(256), 0, stream, hist, cursor);
    hipLaunchKernelGGL(k_scatter, dim3((N_EDGES + 255) / 256), dim3(256), 0, stream, dst, cursor, perm);
    hipLaunchKernelGGL(k_prepw, dim3((384 * D + 255) / 256), dim3(256), 0, stream, wp, wpT);
    hipLaunchKernelGGL(k_pretrans, dim3(N_EDGES / 64), dim3(256), 0, stream,
                       nf, ef, wpT, bp, src, dst, perm, s1, s2, mx, mn);
    hipLaunchKernelGGL(k_finalize, dim3((unsigned)((ND + 255) / 256)), dim3(256), 0, stream,
                       s1, s2, mx, mn, hist, scal);
    hipLaunchKernelGGL(k_post1, dim3((N_NODES + 63) / 64), dim3(256), 0, stream,
                       nf, s1, mx, mn, s2, scal, w1, b1, h1);
    hipLaunchKernelGGL(k_post2, dim3((N_NODES + 63) / 64), dim3(256), 0, stream,
                       h1, w2, b2, nf, out);
}

// Round 5
// 681.850 us; speedup vs baseline: 14.7109x; 1.6586x over previous
//
#include <hip/hip_runtime.h>
#include <math.h>

#define N_NODES 50000
#define N_EDGES 800000
#define D 128
#define AVG_D_LOG 2.833213344056216f  /* log(17.0) */
#define EPS 1e-5f

typedef __attribute__((ext_vector_type(8))) short bf16x8;
typedef __attribute__((ext_vector_type(4))) float f32x4;

__device__ __forceinline__ unsigned short f2bf(float x) {
    unsigned u = __float_as_uint(x);
    u += 0x7fffu + ((u >> 16) & 1u);
    return (unsigned short)(u >> 16);
}
__device__ __forceinline__ unsigned pk2bf(float a, float b) {
    return (unsigned)f2bf(a) | ((unsigned)f2bf(b) << 16);
}

// ---------------- init: zero accumulators, +inf for min, zero hist ----------------
__global__ void k_init(int* hist, float* s1, float* s2, float* mx, float* mn) {
    size_t stride = (size_t)gridDim.x * blockDim.x;
    size_t i0 = (size_t)blockIdx.x * blockDim.x + threadIdx.x;
    const size_t ND = (size_t)N_NODES * D;
    for (size_t t = i0; t < ND; t += stride) {
        s1[t] = 0.f; s2[t] = 0.f; mx[t] = 0.f;
        ((int*)mn)[t] = 0x7f800000;  // +inf
    }
    for (size_t t = i0; t < N_NODES; t += stride) hist[t] = 0;
}

// ---------------- CSR build ----------------
__global__ void k_hist(const int* __restrict__ dst, int* hist) {
    int e = blockIdx.x * blockDim.x + threadIdx.x;
    if (e < N_EDGES) atomicAdd(&hist[dst[e]], 1);
}

__global__ void k_scan(const int* __restrict__ hist, int* cursor) {
    __shared__ int part[256];
    __shared__ int base_s[256];
    int t = threadIdx.x;
    const int chunk = (N_NODES + 255) / 256;
    int lo = t * chunk;
    int hi = lo + chunk; if (hi > N_NODES) hi = N_NODES;
    int s = 0;
    for (int i = lo; i < hi; ++i) s += hist[i];
    part[t] = s;
    __syncthreads();
    if (t == 0) {
        int run = 0;
        for (int i = 0; i < 256; ++i) { base_s[i] = run; run += part[i]; }
    }
    __syncthreads();
    int run = base_s[t];
    for (int i = lo; i < hi; ++i) { cursor[i] = run; run += hist[i]; }
}

__global__ void k_scatter(const int* __restrict__ dst, int* cursor, int* perm) {
    int e = blockIdx.x * blockDim.x + threadIdx.x;
    if (e < N_EDGES) {
        int pos = atomicAdd(&cursor[dst[e]], 1);
        perm[pos] = e;
    }
}

// ---------------- one-time: W [K][128] fp32 -> WT [128][K] bf16 ----------------
__global__ void k_prepT(const float* __restrict__ w, unsigned short* __restrict__ wT, int K) {
    int idx = blockIdx.x * blockDim.x + threadIdx.x;
    if (idx >= K * D) return;
    int k = idx >> 7, c = idx & 127;
    wT[(size_t)c * K + k] = f2bf(w[idx]);
}

// ---------------- pretrans edge MLP (bf16 MFMA, CK=128) + segmented ALL-ATOMIC scatter ---
// Round-3-verified structure: tile 64 dst-sorted edges x 128 out, K=384 in 3 chunks of 128.
// Epilogue: per-segment reduce in LDS, ATOMIC merge for every segment (no direct-store
// hybrid -> no cross-block write-ownership hazard class at all).
__global__ __launch_bounds__(256) void k_pretrans(
    const float* __restrict__ nf, const float* __restrict__ ef,
    const unsigned short* __restrict__ wpT, const float* __restrict__ bp,
    const int* __restrict__ src, const int* __restrict__ dst,
    const int* __restrict__ perm,
    float* s1, float* s2, float* mx, float* mn)
{
    __shared__ __align__(16) char smem[49152]; // W 32KB @0, z 16KB @32768 | msgT fp32 [128][65] @0
    float* msgT = (float*)smem;
    __shared__ int pidx[64], sidx[64], didx[64];
    __shared__ int seg_start[65], seg_dst[64];
    __shared__ int nseg_s;
    __shared__ float sb[128];

    int t = threadIdx.x;
    int e0 = blockIdx.x * 64;
    if (t < 64) {
        int pe = perm[e0 + t];
        pidx[t] = pe; sidx[t] = src[pe]; didx[t] = dst[pe];
    }
    if (t < 128) sb[t] = bp[t];
    __syncthreads();

    int w  = t >> 6;   // wave 0..3 -> channels w*32..w*32+31
    int l  = t & 63;
    int lr = l & 15;
    int lg = l >> 4;

    f32x4 acc[2][4];
    #pragma unroll
    for (int i = 0; i < 2; ++i)
        #pragma unroll
        for (int j = 0; j < 4; ++j) acc[i][j] = (f32x4){0.f, 0.f, 0.f, 0.f};

    for (int chunk = 0; chunk < 3; ++chunk) {
        // W chunk: [128 c][128 k] bf16, byte = c*256 + ((j*16) ^ ((c&7)<<4))
        #pragma unroll
        for (int p = 0; p < 8; ++p) {
            int g = t + 256 * p;           // 0..2047
            int c = g >> 4, j = g & 15;
            uint4 wv = *(const uint4*)(wpT + (size_t)c * 384 + chunk * 128 + j * 8);
            *(uint4*)(smem + c * 256 + ((j * 16) ^ ((c & 7) << 4))) = wv;
        }
        // z chunk: [64 e][128 k] bf16 @32768
        #pragma unroll
        for (int p = 0; p < 8; ++p) {
            int g = t + 256 * p;           // 0..2047
            int e = g >> 5, q = g & 31;
            const float* srcp;
            if (chunk == 0)      srcp = nf + (size_t)sidx[e] * D + q * 4;
            else if (chunk == 1) srcp = nf + (size_t)didx[e] * D + q * 4;
            else                 srcp = ef + (size_t)pidx[e] * D + q * 4;
            float4 fv = *(const float4*)srcp;
            uint2 hv = { pk2bf(fv.x, fv.y), pk2bf(fv.z, fv.w) };
            *(uint2*)(smem + 32768 + e * 256 + ((q * 8) ^ ((e & 7) << 4))) = hv;
        }
        __syncthreads();
        #pragma unroll
        for (int ks = 0; ks < 4; ++ks) {
            bf16x8 afr[2], bfr[4];
            int kb = ks * 64 + lg * 16;
            #pragma unroll
            for (int cf = 0; cf < 2; ++cf) {
                int c = w * 32 + cf * 16 + lr;
                afr[cf] = *(const bf16x8*)(smem + c * 256 + (kb ^ ((c & 7) << 4)));
            }
            #pragma unroll
            for (int eb = 0; eb < 4; ++eb) {
                int e = eb * 16 + lr;
                bfr[eb] = *(const bf16x8*)(smem + 32768 + e * 256 + (kb ^ ((e & 7) << 4)));
            }
            #pragma unroll
            for (int cf = 0; cf < 2; ++cf)
                #pragma unroll
                for (int eb = 0; eb < 4; ++eb)
                    acc[cf][eb] = __builtin_amdgcn_mfma_f32_16x16x32_bf16(
                        afr[cf], bfr[eb], acc[cf][eb], 0, 0, 0);
        }
        __syncthreads();
    }

    // ---- epilogue: bias+relu -> msgT[c][e] fp32, row stride 65 ----
    #pragma unroll
    for (int cf = 0; cf < 2; ++cf)
        #pragma unroll
        for (int eb = 0; eb < 4; ++eb)
            #pragma unroll
            for (int r = 0; r < 4; ++r) {
                int c = w * 32 + cf * 16 + lg * 4 + r;   // D row = (lane>>4)*4+reg
                int e = eb * 16 + lr;                    // D col = lane&15
                msgT[c * 65 + e] = fmaxf(acc[cf][eb][r] + sb[c], 0.f);
            }
    if (t == 0) {
        int ns = 0;
        for (int e = 0; e < 64; ++e) {
            if (e == 0 || didx[e] != didx[e - 1]) { seg_dst[ns] = didx[e]; seg_start[ns] = e; ++ns; }
        }
        seg_start[ns] = 64; nseg_s = ns;
    }
    __syncthreads();
    int nseg = nseg_s;
    for (int idx = t; idx < nseg * D; idx += 256) {
        int sg = idx >> 7, c = idx & 127;
        int eb2 = seg_start[sg], ee = seg_start[sg + 1];
        float s = 0.f, q = 0.f, vmax = 0.f, vmin = __int_as_float(0x7f800000);
        for (int e = eb2; e < ee; ++e) {
            float v = msgT[c * 65 + e];
            s += v; q += v * v;
            vmax = fmaxf(vmax, v); vmin = fminf(vmin, v);
        }
        size_t base = (size_t)seg_dst[sg] * D + c;
        atomicAdd(&s1[base], s);
        atomicAdd(&s2[base], q);
        atomicMax((int*)&mx[base], __float_as_int(vmax));  // msg >= 0
        atomicMin((int*)&mn[base], __float_as_int(vmin));
    }
}

// ---------------- finalize aggregators in-place + per-node scalers ----------------
__global__ void k_finalize(float* s1, float* s2, float* mx, float* mn,
                           const int* __restrict__ hist, float* scal) {
    size_t idx = (size_t)blockIdx.x * blockDim.x + threadIdx.x;
    if (idx >= (size_t)N_NODES * D) return;
    int n = (int)(idx >> 7);
    int c = (int)(idx & 127);
    float dg = (float)hist[n];
    float ds = fmaxf(dg, 1.f);
    float m  = s1[idx] / ds;
    float var = fmaxf(s2[idx] / ds - m * m, 0.f);
    float sd  = sqrtf(var + EPS);
    bool nb = dg > 0.f;
    s1[idx] = m;
    mx[idx] = nb ? mx[idx] : 0.f;
    mn[idx] = nb ? mn[idx] : 0.f;
    s2[idx] = sd;
    if (c == 0) {
        float logd = logf(dg + 1.f);
        scal[2 * n]     = logd / AVG_D_LOG;
        scal[2 * n + 1] = AVG_D_LOG / fmaxf(logd, EPS);
    }
}

// ---------------- posttrans1 (bf16 MFMA): h1 = relu(h @ w_post1 + b1) -> bf16 ----
__global__ __launch_bounds__(256, 3) void k_post1(
    const float* __restrict__ nf,
    const float* __restrict__ amean, const float* __restrict__ amax,
    const float* __restrict__ amin,  const float* __restrict__ astd,
    const float* __restrict__ scal,
    const unsigned short* __restrict__ w1T, const float* __restrict__ b1,
    unsigned short* __restrict__ h1bf)
{
    __shared__ __align__(16) char smem[49152]; // W 32KB @0, B 16KB @32768
    __shared__ float samp[64], satt[64], sb[128];

    int t = threadIdx.x;
    int n0 = blockIdx.x * 64;
    if (t < 64) {
        int n = n0 + t;
        samp[t] = (n < N_NODES) ? scal[2 * n] : 0.f;
        satt[t] = (n < N_NODES) ? scal[2 * n + 1] : 0.f;
    }
    if (t < 128) sb[t] = b1[t];
    __syncthreads();

    int w  = t >> 6, l = t & 63, lr = l & 15, lg = l >> 4;
    f32x4 acc[2][4];
    #pragma unroll
    for (int i = 0; i < 2; ++i)
        #pragma unroll
        for (int j = 0; j < 4; ++j) acc[i][j] = (f32x4){0.f, 0.f, 0.f, 0.f};

    for (int chunk = 0; chunk < 13; ++chunk) {
        // W chunk [128 c][128 k]
        #pragma unroll
        for (int p = 0; p < 8; ++p) {
            int g = t + 256 * p;
            int c = g >> 4, j = g & 15;
            uint4 wv = *(const uint4*)(w1T + (size_t)c * 1664 + chunk * 128 + j * 8);
            *(uint4*)(smem + c * 256 + ((j * 16) ^ ((c & 7) << 4))) = wv;
        }
        // B chunk [64 n][128 k] with fused scaling
        const float* base;
        int r;
        if (chunk == 0) { base = nf; r = 0; }
        else {
            int b = (chunk - 1) & 3;
            r = (chunk - 1) >> 2;   // 0:identity, 1:amp, 2:att
            base = (b == 0) ? amean : (b == 1) ? amax : (b == 2) ? amin : astd;
        }
        #pragma unroll
        for (int p = 0; p < 8; ++p) {
            int g = t + 256 * p;
            int e = g >> 5, q = g & 31;
            int n = n0 + e;
            float4 fv = {0.f, 0.f, 0.f, 0.f};
            if (n < N_NODES) {
                fv = *(const float4*)(base + (size_t)n * D + q * 4);
                if (r == 1) { float sc = samp[e]; fv.x *= sc; fv.y *= sc; fv.z *= sc; fv.w *= sc; }
                else if (r == 2) { float sc = satt[e]; fv.x *= sc; fv.y *= sc; fv.z *= sc; fv.w *= sc; }
            }
            uint2 hv = { pk2bf(fv.x, fv.y), pk2bf(fv.z, fv.w) };
            *(uint2*)(smem + 32768 + e * 256 + ((q * 8) ^ ((e & 7) << 4))) = hv;
        }
        __syncthreads();
        #pragma unroll
        for (int ks = 0; ks < 4; ++ks) {
            bf16x8 afr[2], bfr[4];
            int kb = ks * 64 + lg * 16;
            #pragma unroll
            for (int cf = 0; cf < 2; ++cf) {
                int c = w * 32 + cf * 16 + lr;
                afr[cf] = *(const bf16x8*)(smem + c * 256 + (kb ^ ((c & 7) << 4)));
            }
            #pragma unroll
            for (int eb = 0; eb < 4; ++eb) {
                int e = eb * 16 + lr;
                bfr[eb] = *(const bf16x8*)(smem + 32768 + e * 256 + (kb ^ ((e & 7) << 4)));
            }
            #pragma unroll
            for (int cf = 0; cf < 2; ++cf)
                #pragma unroll
                for (int eb = 0; eb < 4; ++eb)
                    acc[cf][eb] = __builtin_amdgcn_mfma_f32_16x16x32_bf16(
                        afr[cf], bfr[eb], acc[cf][eb], 0, 0, 0);
        }
        __syncthreads();
    }

    // epilogue: relu(acc + b1) -> h1 bf16
    #pragma unroll
    for (int cf = 0; cf < 2; ++cf)
        #pragma unroll
        for (int eb = 0; eb < 4; ++eb) {
            int n = n0 + eb * 16 + lr;
            if (n < N_NODES) {
                int c0 = w * 32 + cf * 16 + lg * 4;
                float v0 = fmaxf(acc[cf][eb][0] + sb[c0 + 0], 0.f);
                float v1 = fmaxf(acc[cf][eb][1] + sb[c0 + 1], 0.f);
                float v2 = fmaxf(acc[cf][eb][2] + sb[c0 + 2], 0.f);
                float v3 = fmaxf(acc[cf][eb][3] + sb[c0 + 3], 0.f);
                uint2 hv = { pk2bf(v0, v1), pk2bf(v2, v3) };
                *(uint2*)(h1bf + (size_t)n * D + c0) = hv;
            }
        }
}

// ---------------- posttrans2 (bf16 MFMA): out = h1 @ w_post2 + b2 + nf ----------------
__global__ __launch_bounds__(256, 3) void k_post2(
    const unsigned short* __restrict__ h1bf, const unsigned short* __restrict__ w2T,
    const float* __restrict__ b2, const float* __restrict__ nf,
    float* __restrict__ out)
{
    __shared__ __align__(16) char smem[49152]; // W 32KB @0, B 16KB @32768
    __shared__ float sb[128];

    int t = threadIdx.x;
    int n0 = blockIdx.x * 64;
    if (t < 128) sb[t] = b2[t];

    int w  = t >> 6, l = t & 63, lr = l & 15, lg = l >> 4;
    f32x4 acc[2][4];
    #pragma unroll
    for (int i = 0; i < 2; ++i)
        #pragma unroll
        for (int j = 0; j < 4; ++j) acc[i][j] = (f32x4){0.f, 0.f, 0.f, 0.f};

    // stage W2 [128][128]
    #pragma unroll
    for (int p = 0; p < 8; ++p) {
        int g = t + 256 * p;
        int c = g >> 4, j = g & 15;
        uint4 wv = *(const uint4*)(w2T + (size_t)c * 128 + j * 8);
        *(uint4*)(smem + c * 256 + ((j * 16) ^ ((c & 7) << 4))) = wv;
    }
    // stage B = h1 [64 n][128 k] bf16
    #pragma unroll
    for (int p = 0; p < 4; ++p) {
        int g = t + 256 * p;
        int e = g >> 4, j = g & 15;
        int n = n0 + e;
        uint4 hv = {0u, 0u, 0u, 0u};
        if (n < N_NODES) hv = *(const uint4*)(h1bf + (size_t)n * D + j * 8);
        *(uint4*)(smem + 32768 + e * 256 + ((j * 16) ^ ((e & 7) << 4))) = hv;
    }
    __syncthreads();
    #pragma unroll
    for (int ks = 0; ks < 4; ++ks) {
        bf16x8 afr[2], bfr[4];
        int kb = ks * 64 + lg * 16;
        #pragma unroll
        for (int cf = 0; cf < 2; ++cf) {
            int c = w * 32 + cf * 16 + lr;
            afr[cf] = *(const bf16x8*)(smem + c * 256 + (kb ^ ((c & 7) << 4)));
        }
        #pragma unroll
        for (int eb = 0; eb < 4; ++eb) {
            int e = eb * 16 + lr;
            bfr[eb] = *(const bf16x8*)(smem + 32768 + e * 256 + (kb ^ ((e & 7) << 4)));
        }
        #pragma unroll
        for (int cf = 0; cf < 2; ++cf)
            #pragma unroll
            for (int eb = 0; eb < 4; ++eb)
                acc[cf][eb] = __builtin_amdgcn_mfma_f32_16x16x32_bf16(
                    afr[cf], bfr[eb], acc[cf][eb], 0, 0, 0);
    }

    // epilogue: + b2 + nf residual (fp32), direct store
    #pragma unroll
    for (int cf = 0; cf < 2; ++cf)
        #pragma unroll
        for (int eb = 0; eb < 4; ++eb) {
            int n = n0 + eb * 16 + lr;
            if (n < N_NODES) {
                int c0 = w * 32 + cf * 16 + lg * 4;
                float4 rv = *(const float4*)(nf + (size_t)n * D + c0);
                float4 ov = { acc[cf][eb][0] + sb[c0 + 0] + rv.x,
                              acc[cf][eb][1] + sb[c0 + 1] + rv.y,
                              acc[cf][eb][2] + sb[c0 + 2] + rv.z,
                              acc[cf][eb][3] + sb[c0 + 3] + rv.w };
                *(float4*)(out + (size_t)n * D + c0) = ov;
            }
        }
}

extern "C" void kernel_launch(void* const* d_in, const int* in_sizes, int n_in,
                              void* d_out, int out_size, void* d_ws, size_t ws_size,
                              hipStream_t stream) {
    const float* nf = (const float*)d_in[0];
    const float* ef = (const float*)d_in[1];
    const float* wp = (const float*)d_in[2];
    const float* bp = (const float*)d_in[3];
    const float* w1 = (const float*)d_in[4];
    const float* b1 = (const float*)d_in[5];
    const float* w2 = (const float*)d_in[6];
    const float* b2 = (const float*)d_in[7];
    const int* src  = (const int*)d_in[8];
    const int* dst  = (const int*)d_in[9];
    float* out = (float*)d_out;

    const size_t ND = (size_t)N_NODES * D;  // 6.4M
    float* ws     = (float*)d_ws;
    int*   hist   = (int*)ws;                         // 50048
    int*   cursor = hist + 50048;                     // 50048
    int*   perm   = cursor + 50048;                   // 800000
    unsigned short* wpT = (unsigned short*)(perm + N_EDGES);  // 128*384
    unsigned short* w1T = wpT + 49152;                // 128*1664
    unsigned short* w2T = w1T + 212992;               // 128*128
    float* s1     = (float*)(w2T + 16384);            // ND -> mean
    float* s2     = s1 + ND;                          // ND -> std
    float* mx     = s2 + ND;                          // ND -> max
    float* mn     = mx + ND;                          // ND -> min
    float* scal   = mn + ND;                          // 2N (padded 100096)
    unsigned short* h1bf = (unsigned short*)(scal + 100096);  // ND bf16

    hipLaunchKernelGGL(k_init, dim3(2048), dim3(256), 0, stream, hist, s1, s2, mx, mn);
    hipLaunchKernelGGL(k_hist, dim3((N_EDGES + 255) / 256), dim3(256), 0, stream, dst, hist);
    hipLaunchKernelGGL(k_scan, dim3(1), dim3(256), 0, stream, hist, cursor);
    hipLaunchKernelGGL(k_scatter, dim3((N_EDGES + 255) / 256), dim3(256), 0, stream, dst, cursor, perm);
    hipLaunchKernelGGL(k_prepT, dim3(192), dim3(256), 0, stream, wp, wpT, 384);
    hipLaunchKernelGGL(k_prepT, dim3(832), dim3(256), 0, stream, w1, w1T, 1664);
    hipLaunchKernelGGL(k_prepT, dim3(64),  dim3(256), 0, stream, w2, w2T, 128);
    hipLaunchKernelGGL(k_pretrans, dim3(N_EDGES / 64), dim3(256), 0, stream,
                       nf, ef, wpT, bp, src, dst, perm, s1, s2, mx, mn);
    hipLaunchKernelGGL(k_finalize, dim3((unsigned)((ND + 255) / 256)), dim3(256), 0, stream,
                       s1, s2, mx, mn, hist, scal);
    hipLaunchKernelGGL(k_post1, dim3((N_NODES + 63) / 64), dim3(256), 0, stream,
                       nf, s1, mx, mn, s2, scal, w1T, b1, h1bf);
    hipLaunchKernelGGL(k_post2, dim3((N_NODES + 63) / 64), dim3(256), 0, stream,
                       h1bf, w2T, b2, nf, out);
}

// Round 6
// 666.337 us; speedup vs baseline: 15.0534x; 1.0233x over previous
//
#include <hip/hip_runtime.h>
#include <math.h>

#define N_NODES 50000
#define N_EDGES 800000
#define D 128
#define AVG_D_LOG 2.833213344056216f  /* log(17.0) */
#define EPS 1e-5f

typedef __attribute__((ext_vector_type(8))) short bf16x8;
typedef __attribute__((ext_vector_type(4))) float f32x4;

__device__ __forceinline__ unsigned short f2bf(float x) {
    unsigned u = __float_as_uint(x);
    u += 0x7fffu + ((u >> 16) & 1u);
    return (unsigned short)(u >> 16);
}
__device__ __forceinline__ unsigned pk2bf(float a, float b) {
    return (unsigned)f2bf(a) | ((unsigned)f2bf(b) << 16);
}
__device__ __forceinline__ float bf2f(unsigned short u) {
    return __uint_as_float(((unsigned)u) << 16);
}

// ---------------- init: zero accumulators, +inf for min, zero hist ----------------
__global__ void k_init(int* hist, float* s1, float* s2, float* mx, float* mn) {
    size_t stride = (size_t)gridDim.x * blockDim.x;
    size_t i0 = (size_t)blockIdx.x * blockDim.x + threadIdx.x;
    const size_t ND4 = (size_t)N_NODES * D / 4;
    float4 z4 = {0.f, 0.f, 0.f, 0.f};
    int4 inf4 = {0x7f800000, 0x7f800000, 0x7f800000, 0x7f800000};
    for (size_t t = i0; t < ND4; t += stride) {
        ((float4*)s1)[t] = z4; ((float4*)s2)[t] = z4; ((float4*)mx)[t] = z4;
        ((int4*)mn)[t] = inf4;
    }
    for (size_t t = i0; t < N_NODES; t += stride) hist[t] = 0;
}

// ---------------- CSR build ----------------
__global__ void k_hist(const int* __restrict__ dst, int* hist) {
    int e = blockIdx.x * blockDim.x + threadIdx.x;
    if (e < N_EDGES) atomicAdd(&hist[dst[e]], 1);
}

__global__ void k_scan(const int* __restrict__ hist, int* cursor) {
    __shared__ int part[256];
    __shared__ int base_s[256];
    int t = threadIdx.x;
    const int chunk = (N_NODES + 255) / 256;
    int lo = t * chunk;
    int hi = lo + chunk; if (hi > N_NODES) hi = N_NODES;
    int s = 0;
    for (int i = lo; i < hi; ++i) s += hist[i];
    part[t] = s;
    __syncthreads();
    if (t == 0) {
        int run = 0;
        for (int i = 0; i < 256; ++i) { base_s[i] = run; run += part[i]; }
    }
    __syncthreads();
    int run = base_s[t];
    for (int i = lo; i < hi; ++i) { cursor[i] = run; run += hist[i]; }
}

__global__ void k_scatter(const int* __restrict__ dst, int* cursor, int* perm) {
    int e = blockIdx.x * blockDim.x + threadIdx.x;
    if (e < N_EDGES) {
        int pos = atomicAdd(&cursor[dst[e]], 1);
        perm[pos] = e;
    }
}

// ---------------- one-time: W [K][128] fp32 -> WT [128][K] bf16 ----------------
__global__ void k_prepT(const float* __restrict__ w, unsigned short* __restrict__ wT, int K) {
    int idx = blockIdx.x * blockDim.x + threadIdx.x;
    if (idx >= K * D) return;
    int k = idx >> 7, c = idx & 127;
    wT[(size_t)c * K + k] = f2bf(w[idx]);
}

// ---------------- pretrans edge MLP (bf16 MFMA, CK=64) + segmented ALL-ATOMIC scatter ---
// tile 64 dst-sorted edges x 128 out, K=384 in 6 chunks of 64.
// LDS: W 16KB @0 + z 8KB @16384 (staging) | msg bf16 [64e][128c] swizzled @0 (epilogue).
// ~26.5KB/block -> 5 blocks/CU at VGPR~92 (occupancy lever vs round 5's 48KB/3 blocks).
__global__ __launch_bounds__(256) void k_pretrans(
    const float* __restrict__ nf, const float* __restrict__ ef,
    const unsigned short* __restrict__ wpT, const float* __restrict__ bp,
    const int* __restrict__ src, const int* __restrict__ dst,
    const int* __restrict__ perm,
    float* s1, float* s2, float* mx, float* mn)
{
    __shared__ __align__(16) char smem[24576];
    __shared__ int pidx[64], sidx[64], didx[64];
    __shared__ int seg_start[65], seg_dst[64];
    __shared__ int nseg_s;
    __shared__ float sb[128];

    int t = threadIdx.x;
    int e0 = blockIdx.x * 64;
    if (t < 64) {
        int pe = perm[e0 + t];
        pidx[t] = pe; sidx[t] = src[pe]; didx[t] = dst[pe];
    }
    if (t < 128) sb[t] = bp[t];
    __syncthreads();

    int w  = t >> 6;   // wave 0..3 -> channels w*32..w*32+31
    int l  = t & 63;
    int lr = l & 15;
    int lg = l >> 4;

    f32x4 acc[2][4];
    #pragma unroll
    for (int i = 0; i < 2; ++i)
        #pragma unroll
        for (int j = 0; j < 4; ++j) acc[i][j] = (f32x4){0.f, 0.f, 0.f, 0.f};

    for (int chunk = 0; chunk < 6; ++chunk) {
        // W chunk: [128 c][64 k] bf16, byte = c*128 + ((j*16) ^ ((c&7)<<4))
        #pragma unroll
        for (int p = 0; p < 4; ++p) {
            int g = t + 256 * p;            // 0..1023
            int c = g >> 3, j = g & 7;
            uint4 wv = *(const uint4*)(wpT + (size_t)c * 384 + chunk * 64 + j * 8);
            *(uint4*)(smem + c * 128 + ((j * 16) ^ ((c & 7) << 4))) = wv;
        }
        // z chunk: [64 e][64 k] bf16 @16384
        int sel = chunk >> 1, colOff = (chunk & 1) * 64;
        #pragma unroll
        for (int p = 0; p < 4; ++p) {
            int g = t + 256 * p;            // 0..1023
            int e = g >> 4, q = g & 15;
            const float* srcp;
            if (sel == 0)      srcp = nf + (size_t)sidx[e] * D + colOff + q * 4;
            else if (sel == 1) srcp = nf + (size_t)didx[e] * D + colOff + q * 4;
            else               srcp = ef + (size_t)pidx[e] * D + colOff + q * 4;
            float4 fv = *(const float4*)srcp;
            uint2 hv = { pk2bf(fv.x, fv.y), pk2bf(fv.z, fv.w) };
            *(uint2*)(smem + 16384 + e * 128 + ((q * 8) ^ ((e & 7) << 4))) = hv;
        }
        __syncthreads();
        #pragma unroll
        for (int ks = 0; ks < 2; ++ks) {
            bf16x8 afr[2], bfr[4];
            int kb = ks * 64 + lg * 16;
            #pragma unroll
            for (int cf = 0; cf < 2; ++cf) {
                int c = w * 32 + cf * 16 + lr;
                afr[cf] = *(const bf16x8*)(smem + c * 128 + (kb ^ ((c & 7) << 4)));
            }
            #pragma unroll
            for (int eb = 0; eb < 4; ++eb) {
                int e = eb * 16 + lr;
                bfr[eb] = *(const bf16x8*)(smem + 16384 + e * 128 + (kb ^ ((e & 7) << 4)));
            }
            #pragma unroll
            for (int cf = 0; cf < 2; ++cf)
                #pragma unroll
                for (int eb = 0; eb < 4; ++eb)
                    acc[cf][eb] = __builtin_amdgcn_mfma_f32_16x16x32_bf16(
                        afr[cf], bfr[eb], acc[cf][eb], 0, 0, 0);
        }
        __syncthreads();   // also protects msg-region reuse below on last iter
    }

    // ---- epilogue: bias+relu -> msg bf16 [e][c] swizzled: byte = e*256 + ((2c)^((e&7)<<4)) ----
    #pragma unroll
    for (int cf = 0; cf < 2; ++cf)
        #pragma unroll
        for (int eb = 0; eb < 4; ++eb) {
            int e  = eb * 16 + lr;
            int c0 = w * 32 + cf * 16 + lg * 4;   // D row = (lane>>4)*4+reg
            float v0 = fmaxf(acc[cf][eb][0] + sb[c0 + 0], 0.f);
            float v1 = fmaxf(acc[cf][eb][1] + sb[c0 + 1], 0.f);
            float v2 = fmaxf(acc[cf][eb][2] + sb[c0 + 2], 0.f);
            float v3 = fmaxf(acc[cf][eb][3] + sb[c0 + 3], 0.f);
            uint2 mv = { pk2bf(v0, v1), pk2bf(v2, v3) };
            *(uint2*)(smem + e * 256 + ((c0 * 2) ^ ((e & 7) << 4))) = mv;
        }
    if (t == 0) {
        int ns = 0;
        for (int e = 0; e < 64; ++e) {
            if (e == 0 || didx[e] != didx[e - 1]) { seg_dst[ns] = didx[e]; seg_start[ns] = e; ++ns; }
        }
        seg_start[ns] = 64; nseg_s = ns;
    }
    __syncthreads();
    int nseg = nseg_s;
    for (int idx = t; idx < nseg * D; idx += 256) {
        int sg = idx >> 7, c = idx & 127;
        int eb2 = seg_start[sg], ee = seg_start[sg + 1];
        float s = 0.f, q = 0.f, vmax = 0.f, vmin = __int_as_float(0x7f800000);
        for (int e = eb2; e < ee; ++e) {
            float v = bf2f(*(const unsigned short*)(smem + e * 256 + ((c * 2) ^ ((e & 7) << 4))));
            s += v; q += v * v;
            vmax = fmaxf(vmax, v); vmin = fminf(vmin, v);
        }
        size_t base = (size_t)seg_dst[sg] * D + c;
        atomicAdd(&s1[base], s);
        atomicAdd(&s2[base], q);
        atomicMax((int*)&mx[base], __float_as_int(vmax));  // msg >= 0
        atomicMin((int*)&mn[base], __float_as_int(vmin));
    }
}

// ---------------- finalize aggregators in-place + per-node scalers ----------------
__global__ void k_finalize(float* s1, float* s2, float* mx, float* mn,
                           const int* __restrict__ hist, float* scal) {
    size_t idx = (size_t)blockIdx.x * blockDim.x + threadIdx.x;
    if (idx >= (size_t)N_NODES * D) return;
    int n = (int)(idx >> 7);
    int c = (int)(idx & 127);
    float dg = (float)hist[n];
    float ds = fmaxf(dg, 1.f);
    float m  = s1[idx] / ds;
    float var = fmaxf(s2[idx] / ds - m * m, 0.f);
    float sd  = sqrtf(var + EPS);
    bool nb = dg > 0.f;
    s1[idx] = m;
    mx[idx] = nb ? mx[idx] : 0.f;
    mn[idx] = nb ? mn[idx] : 0.f;
    s2[idx] = sd;
    if (c == 0) {
        float logd = logf(dg + 1.f);
        scal[2 * n]     = logd / AVG_D_LOG;
        scal[2 * n + 1] = AVG_D_LOG / fmaxf(logd, EPS);
    }
}

// ---------------- posttrans1 (bf16 MFMA): h1 = relu(h @ w_post1 + b1) -> bf16 ----
__global__ __launch_bounds__(256, 3) void k_post1(
    const float* __restrict__ nf,
    const float* __restrict__ amean, const float* __restrict__ amax,
    const float* __restrict__ amin,  const float* __restrict__ astd,
    const float* __restrict__ scal,
    const unsigned short* __restrict__ w1T, const float* __restrict__ b1,
    unsigned short* __restrict__ h1bf)
{
    __shared__ __align__(16) char smem[49152]; // W 32KB @0, B 16KB @32768
    __shared__ float samp[64], satt[64], sb[128];

    int t = threadIdx.x;
    int n0 = blockIdx.x * 64;
    if (t < 64) {
        int n = n0 + t;
        samp[t] = (n < N_NODES) ? scal[2 * n] : 0.f;
        satt[t] = (n < N_NODES) ? scal[2 * n + 1] : 0.f;
    }
    if (t < 128) sb[t] = b1[t];
    __syncthreads();

    int w  = t >> 6, l = t & 63, lr = l & 15, lg = l >> 4;
    f32x4 acc[2][4];
    #pragma unroll
    for (int i = 0; i < 2; ++i)
        #pragma unroll
        for (int j = 0; j < 4; ++j) acc[i][j] = (f32x4){0.f, 0.f, 0.f, 0.f};

    for (int chunk = 0; chunk < 13; ++chunk) {
        // W chunk [128 c][128 k]
        #pragma unroll
        for (int p = 0; p < 8; ++p) {
            int g = t + 256 * p;
            int c = g >> 4, j = g & 15;
            uint4 wv = *(const uint4*)(w1T + (size_t)c * 1664 + chunk * 128 + j * 8);
            *(uint4*)(smem + c * 256 + ((j * 16) ^ ((c & 7) << 4))) = wv;
        }
        // B chunk [64 n][128 k] with fused scaling
        const float* base;
        int r;
        if (chunk == 0) { base = nf; r = 0; }
        else {
            int b = (chunk - 1) & 3;
            r = (chunk - 1) >> 2;   // 0:identity, 1:amp, 2:att
            base = (b == 0) ? amean : (b == 1) ? amax : (b == 2) ? amin : astd;
        }
        #pragma unroll
        for (int p = 0; p < 8; ++p) {
            int g = t + 256 * p;
            int e = g >> 5, q = g & 31;
            int n = n0 + e;
            float4 fv = {0.f, 0.f, 0.f, 0.f};
            if (n < N_NODES) {
                fv = *(const float4*)(base + (size_t)n * D + q * 4);
                if (r == 1) { float sc = samp[e]; fv.x *= sc; fv.y *= sc; fv.z *= sc; fv.w *= sc; }
                else if (r == 2) { float sc = satt[e]; fv.x *= sc; fv.y *= sc; fv.z *= sc; fv.w *= sc; }
            }
            uint2 hv = { pk2bf(fv.x, fv.y), pk2bf(fv.z, fv.w) };
            *(uint2*)(smem + 32768 + e * 256 + ((q * 8) ^ ((e & 7) << 4))) = hv;
        }
        __syncthreads();
        #pragma unroll
        for (int ks = 0; ks < 4; ++ks) {
            bf16x8 afr[2], bfr[4];
            int kb = ks * 64 + lg * 16;
            #pragma unroll
            for (int cf = 0; cf < 2; ++cf) {
                int c = w * 32 + cf * 16 + lr;
                afr[cf] = *(const bf16x8*)(smem + c * 256 + (kb ^ ((c & 7) << 4)));
            }
            #pragma unroll
            for (int eb = 0; eb < 4; ++eb) {
                int e = eb * 16 + lr;
                bfr[eb] = *(const bf16x8*)(smem + 32768 + e * 256 + (kb ^ ((e & 7) << 4)));
            }
            #pragma unroll
            for (int cf = 0; cf < 2; ++cf)
                #pragma unroll
                for (int eb = 0; eb < 4; ++eb)
                    acc[cf][eb] = __builtin_amdgcn_mfma_f32_16x16x32_bf16(
                        afr[cf], bfr[eb], acc[cf][eb], 0, 0, 0);
        }
        __syncthreads();
    }

    // epilogue: relu(acc + b1) -> h1 bf16
    #pragma unroll
    for (int cf = 0; cf < 2; ++cf)
        #pragma unroll
        for (int eb = 0; eb < 4; ++eb) {
            int n = n0 + eb * 16 + lr;
            if (n < N_NODES) {
                int c0 = w * 32 + cf * 16 + lg * 4;
                float v0 = fmaxf(acc[cf][eb][0] + sb[c0 + 0], 0.f);
                float v1 = fmaxf(acc[cf][eb][1] + sb[c0 + 1], 0.f);
                float v2 = fmaxf(acc[cf][eb][2] + sb[c0 + 2], 0.f);
                float v3 = fmaxf(acc[cf][eb][3] + sb[c0 + 3], 0.f);
                uint2 hv = { pk2bf(v0, v1), pk2bf(v2, v3) };
                *(uint2*)(h1bf + (size_t)n * D + c0) = hv;
            }
        }
}

// ---------------- posttrans2 (bf16 MFMA): out = h1 @ w_post2 + b2 + nf ----------------
__global__ __launch_bounds__(256, 3) void k_post2(
    const unsigned short* __restrict__ h1bf, const unsigned short* __restrict__ w2T,
    const float* __restrict__ b2, const float* __restrict__ nf,
    float* __restrict__ out)
{
    __shared__ __align__(16) char smem[49152]; // W 32KB @0, B 16KB @32768
    __shared__ float sb[128];

    int t = threadIdx.x;
    int n0 = blockIdx.x * 64;
    if (t < 128) sb[t] = b2[t];

    int w  = t >> 6, l = t & 63, lr = l & 15, lg = l >> 4;
    f32x4 acc[2][4];
    #pragma unroll
    for (int i = 0; i < 2; ++i)
        #pragma unroll
        for (int j = 0; j < 4; ++j) acc[i][j] = (f32x4){0.f, 0.f, 0.f, 0.f};

    // stage W2 [128][128]
    #pragma unroll
    for (int p = 0; p < 8; ++p) {
        int g = t + 256 * p;
        int c = g >> 4, j = g & 15;
        uint4 wv = *(const uint4*)(w2T + (size_t)c * 128 + j * 8);
        *(uint4*)(smem + c * 256 + ((j * 16) ^ ((c & 7) << 4))) = wv;
    }
    // stage B = h1 [64 n][128 k] bf16
    #pragma unroll
    for (int p = 0; p < 4; ++p) {
        int g = t + 256 * p;
        int e = g >> 4, j = g & 15;
        int n = n0 + e;
        uint4 hv = {0u, 0u, 0u, 0u};
        if (n < N_NODES) hv = *(const uint4*)(h1bf + (size_t)n * D + j * 8);
        *(uint4*)(smem + 32768 + e * 256 + ((j * 16) ^ ((e & 7) << 4))) = hv;
    }
    __syncthreads();
    #pragma unroll
    for (int ks = 0; ks < 4; ++ks) {
        bf16x8 afr[2], bfr[4];
        int kb = ks * 64 + lg * 16;
        #pragma unroll
        for (int cf = 0; cf < 2; ++cf) {
            int c = w * 32 + cf * 16 + lr;
            afr[cf] = *(const bf16x8*)(smem + c * 256 + (kb ^ ((c & 7) << 4)));
        }
        #pragma unroll
        for (int eb = 0; eb < 4; ++eb) {
            int e = eb * 16 + lr;
            bfr[eb] = *(const bf16x8*)(smem + 32768 + e * 256 + (kb ^ ((e & 7) << 4)));
        }
        #pragma unroll
        for (int cf = 0; cf < 2; ++cf)
            #pragma unroll
            for (int eb = 0; eb < 4; ++eb)
                acc[cf][eb] = __builtin_amdgcn_mfma_f32_16x16x32_bf16(
                    afr[cf], bfr[eb], acc[cf][eb], 0, 0, 0);
    }

    // epilogue: + b2 + nf residual (fp32), direct store
    #pragma unroll
    for (int cf = 0; cf < 2; ++cf)
        #pragma unroll
        for (int eb = 0; eb < 4; ++eb) {
            int n = n0 + eb * 16 + lr;
            if (n < N_NODES) {
                int c0 = w * 32 + cf * 16 + lg * 4;
                float4 rv = *(const float4*)(nf + (size_t)n * D + c0);
                float4 ov = { acc[cf][eb][0] + sb[c0 + 0] + rv.x,
                              acc[cf][eb][1] + sb[c0 + 1] + rv.y,
                              acc[cf][eb][2] + sb[c0 + 2] + rv.z,
                              acc[cf][eb][3] + sb[c0 + 3] + rv.w };
                *(float4*)(out + (size_t)n * D + c0) = ov;
            }
        }
}

extern "C" void kernel_launch(void* const* d_in, const int* in_sizes, int n_in,
                              void* d_out, int out_size, void* d_ws, size_t ws_size,
                              hipStream_t stream) {
    const float* nf = (const float*)d_in[0];
    const float* ef = (const float*)d_in[1];
    const float* wp = (const float*)d_in[2];
    const float* bp = (const float*)d_in[3];
    const float* w1 = (const float*)d_in[4];
    const float* b1 = (const float*)d_in[5];
    const float* w2 = (const float*)d_in[6];
    const float* b2 = (const float*)d_in[7];
    const int* src  = (const int*)d_in[8];
    const int* dst  = (const int*)d_in[9];
    float* out = (float*)d_out;

    const size_t ND = (size_t)N_NODES * D;  // 6.4M
    float* ws     = (float*)d_ws;
    int*   hist   = (int*)ws;                         // 50048
    int*   cursor = hist + 50048;                     // 50048
    int*   perm   = cursor + 50048;                   // 800000
    unsigned short* wpT = (unsigned short*)(perm + N_EDGES);  // 128*384
    unsigned short* w1T = wpT + 49152;                // 128*1664
    unsigned short* w2T = w1T + 212992;               // 128*128
    float* s1     = (float*)(w2T + 16384);            // ND -> mean
    float* s2     = s1 + ND;                          // ND -> std
    float* mx     = s2 + ND;                          // ND -> max
    float* mn     = mx + ND;                          // ND -> min
    float* scal   = mn + ND;                          // 2N (padded 100096)
    unsigned short* h1bf = (unsigned short*)(scal + 100096);  // ND bf16

    hipLaunchKernelGGL(k_init, dim3(2048), dim3(256), 0, stream, hist, s1, s2, mx, mn);
    hipLaunchKernelGGL(k_hist, dim3((N_EDGES + 255) / 256), dim3(256), 0, stream, dst, hist);
    hipLaunchKernelGGL(k_scan, dim3(1), dim3(256), 0, stream, hist, cursor);
    hipLaunchKernelGGL(k_scatter, dim3((N_EDGES + 255) / 256), dim3(256), 0, stream, dst, cursor, perm);
    hipLaunchKernelGGL(k_prepT, dim3(192), dim3(256), 0, stream, wp, wpT, 384);
    hipLaunchKernelGGL(k_prepT, dim3(832), dim3(256), 0, stream, w1, w1T, 1664);
    hipLaunchKernelGGL(k_prepT, dim3(64),  dim3(256), 0, stream, w2, w2T, 128);
    hipLaunchKernelGGL(k_pretrans, dim3(N_EDGES / 64), dim3(256), 0, stream,
                       nf, ef, wpT, bp, src, dst, perm, s1, s2, mx, mn);
    hipLaunchKernelGGL(k_finalize, dim3((unsigned)((ND + 255) / 256)), dim3(256), 0, stream,
                       s1, s2, mx, mn, hist, scal);
    hipLaunchKernelGGL(k_post1, dim3((N_NODES + 63) / 64), dim3(256), 0, stream,
                       nf, s1, mx, mn, s2, scal, w1T, b1, h1bf);
    hipLaunchKernelGGL(k_post2, dim3((N_NODES + 63) / 64), dim3(256), 0, stream,
                       h1bf, w2T, b2, nf, out);
}